// Round 1
// 546.767 us; speedup vs baseline: 1.0416x; 1.0416x over previous
//
#include <hip/hip_runtime.h>
#include <hip/hip_bf16.h>

// ---------------------------------------------------------------------------
// parsingNet: pool(1x1 conv 2048->8) -> GAT1(8->4x16) -> GAT2(64->8)
//             -> fc1(1800->2048,relu) -> fc2(2048->20800)
// B=128, grid graph 9x25 (225 nodes, 8-neighborhood + self loop).
// ---------------------------------------------------------------------------

typedef __attribute__((ext_vector_type(8))) short bh8_t;   // 8 x bf16 (4 VGPR)
typedef __attribute__((ext_vector_type(4))) float f32x4;

static __device__ __forceinline__ short f2bs(float f) {
    __hip_bfloat16 h = __float2bfloat16(f);
    return *reinterpret_cast<short*>(&h);
}
static __device__ __forceinline__ unsigned pack2(short a, short b) {
    return (unsigned)(unsigned short)a | ((unsigned)(unsigned short)b << 16);
}

// ---------------------------------------------------------------------------
// Kernel 1: pool partials.  grid = 128 b * 8 chunks.  out[b][chunk][n][o]
// fea_partial[b,ch,n,o] = sum_{c in chunk} x4[b,c,n] * pool_w[o,c]
// Weights are wave-uniform -> read pool_w directly so compiler emits s_load
// (SMEM pipe) instead of the old 2x ds_read_b128 per 4B of global traffic.
// ---------------------------------------------------------------------------
__global__ __launch_bounds__(256) void pool_kernel(const float* __restrict__ x4,
                                                   const float* __restrict__ pool_w,
                                                   float* __restrict__ part) {
    const int b  = blockIdx.x >> 3;
    const int ch = blockIdx.x & 7;
    const int tid = threadIdx.x;
    if (tid >= 225) return;
    const float* xp = x4 + ((size_t)b * 2048 + (size_t)ch * 256) * 225 + tid;
    const float* wp = pool_w + ch * 256;          // pool_w[o*2048 + ch*256 + c], uniform index
    float a[8] = {};
#pragma unroll 8
    for (int c = 0; c < 256; ++c) {
        const float v = xp[c * 225];
#pragma unroll
        for (int o = 0; o < 8; ++o) a[o] += v * wp[o * 2048 + c];
    }
    float* dst = part + (size_t)b * 14400 + ch * 1800 + tid * 8;
    *reinterpret_cast<float4*>(dst)     = make_float4(a[0], a[1], a[2], a[3]);
    *reinterpret_cast<float4*>(dst + 4) = make_float4(a[4], a[5], a[6], a[7]);
}

// ---------------------------------------------------------------------------
// Kernel 2: fused GAT1 + GAT2.  one block per b.
// fea[225][8] -> h1[225][64] -> attn(4 heads,d=16) -> relu -> x1 (in-LDS, h region)
//   -> h2[225][8] -> attn(1 head,d=8) -> flat (bf16, padded to 1824)
// LDS: att 7200B (fea / asrc+adst / h2) + h 57600B (h1 then x1) = 64800B.
// x1 never touches global memory (saves 14.7MB round trip + a launch).
// ---------------------------------------------------------------------------
__global__ __launch_bounds__(256) void gat_kernel(const float* __restrict__ part,
                                                  const float* __restrict__ pool_b,
                                                  const float* __restrict__ w1g,
                                                  const float* __restrict__ a1src,
                                                  const float* __restrict__ a1dst,
                                                  const float* __restrict__ b1g,
                                                  const float* __restrict__ w2g,
                                                  const float* __restrict__ a2src,
                                                  const float* __restrict__ a2dst,
                                                  const float* __restrict__ b2g,
                                                  short* __restrict__ flat) {
    __shared__ __align__(16) float att[1800];   // fea -> [0..899]=asrc,[900..1799]=adst -> h2
    __shared__ __align__(16) float h[14400];    // h1[225][64] -> x1[225][64]
    const int b = blockIdx.x;
    const int tid = threadIdx.x;

    // phase 1: reduce 8 partials -> fea (att region)
    for (int i = tid; i < 1800; i += 256) {
        const float* p = part + (size_t)b * 14400 + i;
        float s = 0;
#pragma unroll
        for (int c = 0; c < 8; ++c) s += p[c * 1800];
        att[i] = s + pool_b[i & 7];
    }
    __syncthreads();

    // phase 2: h1 = fea @ w1g  (225x8 @ 8x64)
    {
        const int o = tid & 63, mr = tid >> 6;
        float wv[8];
#pragma unroll
        for (int k = 0; k < 8; ++k) wv[k] = w1g[k * 64 + o];
        for (int n = mr; n < 225; n += 4) {
            float acc = 0;
#pragma unroll
            for (int k = 0; k < 8; ++k) acc += att[n * 8 + k] * wv[k];
            h[n * 64 + o] = acc;
        }
    }
    __syncthreads();

    // phase 2.5: asrc/adst per (node, head) -> att region (fea dead)
    for (int t = tid; t < 900; t += 256) {
        const int n = t >> 2, hd = t & 3;
        const float* hp = &h[n * 64 + hd * 16];
        float as = 0, ad = 0;
#pragma unroll
        for (int d = 0; d < 16; ++d) {
            float hv = hp[d];
            as += hv * a1src[hd * 16 + d];
            ad += hv * a1dst[hd * 16 + d];
        }
        att[t] = as;
        att[900 + t] = ad;
    }
    __syncthreads();

    // phase 3: GAT1 attention + relu + bias -> registers (h still needed by others)
    float o1[4][16];
#pragma unroll
    for (int r = 0; r < 4; ++r) {
        const int task = tid + 256 * r;
        if (task < 900) {
            const int n = task >> 2, hd = task & 3;
            const int i = n / 25, j = n % 25;
            const float adn = att[900 + task];
            float e[9];
            int sid[9];
            float mx = -1e30f;
#pragma unroll
            for (int t9 = 0; t9 < 9; ++t9) {
                const int di = t9 / 3 - 1, dj = t9 % 3 - 1;
                const int ni = i + di, nj = j + dj;
                const bool valid = ((unsigned)ni < 9u) && ((unsigned)nj < 25u);
                const int s = valid ? ni * 25 + nj : n;
                sid[t9] = s;
                float ev = att[s * 4 + hd] + adn;
                ev = ev >= 0.f ? ev : 0.2f * ev;          // leaky_relu(0.2)
                e[t9] = valid ? ev : -1e30f;
                mx = fmaxf(mx, e[t9]);
            }
            float sum = 0;
#pragma unroll
            for (int t9 = 0; t9 < 9; ++t9) {
                float ex = __expf(e[t9] - mx);
                e[t9] = ex;
                sum += ex;
            }
            const float inv = 1.f / sum;
            float out[16] = {};
#pragma unroll
            for (int t9 = 0; t9 < 9; ++t9) {
                const float al = e[t9] * inv;
                const float* hp = &h[sid[t9] * 64 + hd * 16];
#pragma unroll
                for (int d = 0; d < 16; ++d) out[d] += al * hp[d];
            }
            const float* bp = b1g + hd * 16;
#pragma unroll
            for (int d = 0; d < 16; ++d) o1[r][d] = fmaxf(out[d] + bp[d], 0.f);
        }
    }
    __syncthreads();   // all reads of h1 complete

    // phase 4: x1 -> h region
#pragma unroll
    for (int r = 0; r < 4; ++r) {
        const int task = tid + 256 * r;
        if (task < 900) {
            const int n = task >> 2, hd = task & 3;
#pragma unroll
            for (int d = 0; d < 16; ++d) h[n * 64 + hd * 16 + d] = o1[r][d];
        }
    }
    __syncthreads();

    // phase 5: h2 = x1 @ w2g (225x64 @ 64x8) -> att region (asrc/adst dead)
    if (tid < 225) {
        const int n = tid;
        float acc8[8] = {};
#pragma unroll 4
        for (int k = 0; k < 64; k += 4) {
            const float4 xv = *reinterpret_cast<const float4*>(&h[n * 64 + k]);
#pragma unroll
            for (int o = 0; o < 8; ++o) {
                acc8[o] += xv.x * w2g[k * 8 + o] + xv.y * w2g[(k + 1) * 8 + o]
                         + xv.z * w2g[(k + 2) * 8 + o] + xv.w * w2g[(k + 3) * 8 + o];
            }
        }
#pragma unroll
        for (int o = 0; o < 8; ++o) att[n * 8 + o] = acc8[o];
    }
    __syncthreads();

    // phase 6: GAT2 attention (1 head, d=8, mean==identity) -> flat (bf16)
    if (tid < 225) {
        const int n = tid, i = n / 25, j = n % 25;
        float av[8], dv[8];
#pragma unroll
        for (int d = 0; d < 8; ++d) { av[d] = a2src[d]; dv[d] = a2dst[d]; }
        float adn = 0;
#pragma unroll
        for (int d = 0; d < 8; ++d) adn += att[n * 8 + d] * dv[d];
        float e[9];
        int sid[9];
        float mx = -1e30f;
#pragma unroll
        for (int t9 = 0; t9 < 9; ++t9) {
            const int di = t9 / 3 - 1, dj = t9 % 3 - 1;
            const int ni = i + di, nj = j + dj;
            const bool valid = ((unsigned)ni < 9u) && ((unsigned)nj < 25u);
            const int s = valid ? ni * 25 + nj : n;
            sid[t9] = s;
            float as = 0;
#pragma unroll
            for (int d = 0; d < 8; ++d) as += att[s * 8 + d] * av[d];
            float ev = as + adn;
            ev = ev >= 0.f ? ev : 0.2f * ev;
            e[t9] = valid ? ev : -1e30f;
            mx = fmaxf(mx, e[t9]);
        }
        float sum = 0;
#pragma unroll
        for (int t9 = 0; t9 < 9; ++t9) {
            float ex = __expf(e[t9] - mx);
            e[t9] = ex;
            sum += ex;
        }
        const float inv = 1.f / sum;
        float out[8] = {};
#pragma unroll
        for (int t9 = 0; t9 < 9; ++t9) {
            const float al = e[t9] * inv;
            const float* hp = &att[sid[t9] * 8];
#pragma unroll
            for (int d = 0; d < 8; ++d) out[d] += al * hp[d];
        }
        short* dst = flat + (size_t)b * 1824 + n * 8;
#pragma unroll
        for (int d = 0; d < 8; ++d) dst[d] = f2bs(out[d] + b2g[d]);
    }
    // zero-pad K 1800 -> 1824 so fc1 has no boundary tile
    if (tid < 24) flat[(size_t)b * 1824 + 1800 + tid] = 0;
}

// ---------------------------------------------------------------------------
// Kernel 3/4: MFMA GEMM  C[128,N] = A_bf16[128,K] @ bf16(Wf[Kw,N]) (+bias, opt relu)
// BM=128, BK=32, 256 threads (4 waves), 16x16x32 bf16 MFMA.
// K is the padded A stride (multiple of 32); Kw the valid W row count
// (W row index clamped for k>=Kw; A is zero there so the product is 0).
// Double-buffered LDS, T3-minimum 2-phase: issue next tile's global loads
// BEFORE this tile's MFMA, ds_write after, ONE barrier per k-tile.
// LDS rows padded to 40 bf16 (80B, 16B-aligned, conflict-free b128 frags).
// ---------------------------------------------------------------------------
template <int BN, int MT, int NT, int NWN, bool RELU, bool OUT_BF16>
__global__ __launch_bounds__(256) void gemm_mfma(const short* __restrict__ A,
                                                 const float* __restrict__ Wf,
                                                 const float* __restrict__ bias,
                                                 void* __restrict__ outp,
                                                 int K, int Kw, int N) {
    constexpr int LDT = 40;
    __shared__ __align__(16) short sA[2][128 * LDT];
    __shared__ __align__(16) short sB[2][BN * LDT];   // transposed: [n][k]
    const int tid = threadIdx.x;
    const int lane = tid & 63;
    const int wave = tid >> 6;
    const int n0 = blockIdx.x * BN;
    const int wm0 = (wave / NWN) * (MT * 16);
    const int wn0 = (wave % NWN) * (NT * 16);
    const int lm = lane & 15;
    const int lkb = (lane >> 4) * 8;

    const int am = tid >> 1;          // A row 0..127
    const int akh = tid & 1;          // k half (16 elems)
    constexpr int EPT = (32 * BN) / 256;
    const int bn_ = tid % BN;
    const int bk0 = (tid / BN) * EPT;

    f32x4 acc[MT][NT] = {};
    const int nkt = K >> 5;           // K is a multiple of 32 by construction

    uint4 va0, va1;                   // staged A (32B/thread)
    float bv[EPT];                    // staged W (fp32, converted on ds_write)

    auto LOAD = [&](int kt) {
        const int k0 = kt << 5;
        const uint4* src = reinterpret_cast<const uint4*>(A + (size_t)am * K + k0 + akh * 16);
        va0 = src[0];
        va1 = src[1];
#pragma unroll
        for (int jj = 0; jj < EPT; ++jj) {
            int kk = k0 + bk0 + jj;
            if (kk >= Kw) kk = Kw - 1;              // A==0 there; avoid OOB/NaN
            bv[jj] = Wf[(size_t)kk * N + n0 + bn_];
        }
    };
    auto STORE = [&](int buf) {
        uint4* dstA = reinterpret_cast<uint4*>(&sA[buf][am * LDT + akh * 16]);
        dstA[0] = va0;
        dstA[1] = va1;
        unsigned uw[EPT / 2];
#pragma unroll
        for (int jj = 0; jj < EPT / 2; ++jj)
            uw[jj] = pack2(f2bs(bv[2 * jj]), f2bs(bv[2 * jj + 1]));
        if constexpr (EPT == 8) {
            uint4 u;
            u.x = uw[0]; u.y = uw[1]; u.z = uw[2]; u.w = uw[3];
            *reinterpret_cast<uint4*>(&sB[buf][bn_ * LDT + bk0]) = u;
        } else {
            *reinterpret_cast<unsigned*>(&sB[buf][bn_ * LDT + bk0]) = uw[0];
        }
    };

    LOAD(0);
    STORE(0);
    __syncthreads();

    int cur = 0;
    for (int kt = 0; kt < nkt; ++kt) {
        const bool more = (kt + 1 < nkt);
        if (more) LOAD(kt + 1);                 // issue next-tile loads early
        bh8_t bfr[NT];
#pragma unroll
        for (int nt = 0; nt < NT; ++nt)
            bfr[nt] = *reinterpret_cast<const bh8_t*>(&sB[cur][(wn0 + nt * 16 + lm) * LDT + lkb]);
#pragma unroll
        for (int mt = 0; mt < MT; ++mt) {
            bh8_t afr = *reinterpret_cast<const bh8_t*>(&sA[cur][(wm0 + mt * 16 + lm) * LDT + lkb]);
#pragma unroll
            for (int nt = 0; nt < NT; ++nt)
                acc[mt][nt] = __builtin_amdgcn_mfma_f32_16x16x32_bf16(afr, bfr[nt], acc[mt][nt], 0, 0, 0);
        }
        if (more) STORE(cur ^ 1);               // write-late into the other buffer
        __syncthreads();                        // one barrier per k-tile
        cur ^= 1;
    }

    // epilogue: C/D layout col=lane&15, row=(lane>>4)*4+r  [m89 verified]
    const int rg = lane >> 4;
#pragma unroll
    for (int nt = 0; nt < NT; ++nt) {
        const int n = n0 + wn0 + nt * 16 + lm;
        const float bvv = bias[n];
#pragma unroll
        for (int mt = 0; mt < MT; ++mt) {
#pragma unroll
            for (int r = 0; r < 4; ++r) {
                const int m = wm0 + mt * 16 + rg * 4 + r;
                float v = acc[mt][nt][r] + bvv;
                if (RELU) v = fmaxf(v, 0.f);
                if (OUT_BF16)
                    reinterpret_cast<short*>(outp)[(size_t)m * N + n] = f2bs(v);
                else
                    reinterpret_cast<float*>(outp)[(size_t)m * N + n] = v;
            }
        }
    }
}

// ---------------------------------------------------------------------------
extern "C" void kernel_launch(void* const* d_in, const int* in_sizes, int n_in,
                              void* d_out, int out_size, void* d_ws, size_t ws_size,
                              hipStream_t stream) {
    const float* x4        = (const float*)d_in[0];
    const float* pool_w    = (const float*)d_in[1];
    const float* pool_b    = (const float*)d_in[2];
    const float* gat1_w    = (const float*)d_in[3];
    const float* gat1_asrc = (const float*)d_in[4];
    const float* gat1_adst = (const float*)d_in[5];
    const float* gat1_b    = (const float*)d_in[6];
    const float* gat2_w    = (const float*)d_in[7];
    const float* gat2_asrc = (const float*)d_in[8];
    const float* gat2_adst = (const float*)d_in[9];
    const float* gat2_b    = (const float*)d_in[10];
    const float* w1        = (const float*)d_in[11];
    const float* b1        = (const float*)d_in[12];
    const float* w2        = (const float*)d_in[13];
    const float* b2        = (const float*)d_in[14];
    // d_in[15] edge_index: fixed 9x25 grid, hardcoded in kernels.
    float* out = (float*)d_out;

    char* ws = (char*)d_ws;
    float* part = (float*)ws;                        // 128*8*1800*4 = 7,372,800 B
    short* flat = (short*)(ws + 7372800);            // 128*1824*2  =   466,944 B (K padded)
    short* hid  = (short*)(ws + 7372800 + 466944);   // 128*2048*2  =   524,288 B

    pool_kernel<<<1024, 256, 0, stream>>>(x4, pool_w, part);
    gat_kernel<<<128, 256, 0, stream>>>(part, pool_b, gat1_w, gat1_asrc, gat1_adst, gat1_b,
                                        gat2_w, gat2_asrc, gat2_adst, gat2_b, flat);
    // fc1: K=1824 (zero-padded, no boundary tile), Kw=1800, N=2048, relu, bf16 out
    gemm_mfma<16, 2, 1, 1, true, true><<<128, 256, 0, stream>>>(flat, w1, b1, (void*)hid, 1824, 1800, 2048);
    // fc2: K=2048, N=20800, fp32 out
    gemm_mfma<64, 4, 2, 2, false, false><<<325, 256, 0, stream>>>(hid, w2, b2, (void*)out, 2048, 2048, 20800);
}

// Round 2
// 533.475 us; speedup vs baseline: 1.0675x; 1.0249x over previous
//
#include <hip/hip_runtime.h>
#include <hip/hip_bf16.h>

// ---------------------------------------------------------------------------
// parsingNet: pool(1x1 conv 2048->8) -> GAT1(8->4x16) -> GAT2(64->8)
//             -> fc1(1800->2048,relu) -> fc2(2048->20800)
// B=128, grid graph 9x25 (225 nodes, 8-neighborhood + self loop).
// ---------------------------------------------------------------------------

typedef __attribute__((ext_vector_type(8))) short bh8_t;   // 8 x bf16 (4 VGPR)
typedef __attribute__((ext_vector_type(4))) float f32x4;

static __device__ __forceinline__ short f2bs(float f) {
    __hip_bfloat16 h = __float2bfloat16(f);
    return *reinterpret_cast<short*>(&h);
}
static __device__ __forceinline__ unsigned pack2(short a, short b) {
    return (unsigned)(unsigned short)a | ((unsigned)(unsigned short)b << 16);
}
// h[] LDS swizzle: float4-group g (cols 4g..4g+3) of logical row n lives at
// n*64 + ((g ^ (n&15))<<2).  Row stride 64 == 0 mod 32 banks was a 32-way
// conflict for the per-head reads (bank = (16*hd+d)%32, 2 banks / 64 lanes);
// the XOR spreads groups across all 16 4-bank slots.  16B alignment kept.
static __device__ __forceinline__ int hsw(int n, int g) {
    return n * 64 + ((g ^ (n & 15)) << 2);
}

// ---------------------------------------------------------------------------
// Kernel 1: pool partials.  grid = 128 b * 8 chunks.  out[b][chunk][n][o]
// Weights are wave-uniform -> s_load on the SMEM pipe (no LDS).
// ---------------------------------------------------------------------------
__global__ __launch_bounds__(256) void pool_kernel(const float* __restrict__ x4,
                                                   const float* __restrict__ pool_w,
                                                   float* __restrict__ part) {
    const int b  = blockIdx.x >> 3;
    const int ch = blockIdx.x & 7;
    const int tid = threadIdx.x;
    if (tid >= 225) return;
    const float* xp = x4 + ((size_t)b * 2048 + (size_t)ch * 256) * 225 + tid;
    const float* wp = pool_w + ch * 256;          // pool_w[o*2048 + ch*256 + c], uniform index
    float a[8] = {};
#pragma unroll 8
    for (int c = 0; c < 256; ++c) {
        const float v = xp[c * 225];
#pragma unroll
        for (int o = 0; o < 8; ++o) a[o] += v * wp[o * 2048 + c];
    }
    float* dst = part + (size_t)b * 14400 + ch * 1800 + tid * 8;
    *reinterpret_cast<float4*>(dst)     = make_float4(a[0], a[1], a[2], a[3]);
    *reinterpret_cast<float4*>(dst + 4) = make_float4(a[4], a[5], a[6], a[7]);
}

// ---------------------------------------------------------------------------
// Kernel 2: fused GAT1 + GAT2.  one block per b.
// LDS: att 7200B (fea[225][8] -> asrc[900] -> h2[8][225]) + h 57600B (swizzled
// h1[225][64] then x1).  adst lives in registers (same-thread producer/consumer).
// ---------------------------------------------------------------------------
__global__ __launch_bounds__(256) void gat_kernel(const float* __restrict__ part,
                                                  const float* __restrict__ pool_b,
                                                  const float* __restrict__ w1g,
                                                  const float* __restrict__ a1src,
                                                  const float* __restrict__ a1dst,
                                                  const float* __restrict__ b1g,
                                                  const float* __restrict__ w2g,
                                                  const float* __restrict__ a2src,
                                                  const float* __restrict__ a2dst,
                                                  const float* __restrict__ b2g,
                                                  short* __restrict__ flat) {
    __shared__ __align__(16) float att[1800];   // fea -> asrc -> h2[8][225]
    __shared__ __align__(16) float h[14400];    // swizzled h1 -> x1
    const int b = blockIdx.x;
    const int tid = threadIdx.x;

    // phase 1: reduce 8 partials -> fea (att region, [n][8])
    for (int i = tid; i < 1800; i += 256) {
        const float* p = part + (size_t)b * 14400 + i;
        float s = 0;
#pragma unroll
        for (int c = 0; c < 8; ++c) s += p[c * 1800];
        att[i] = s + pool_b[i & 7];
    }
    __syncthreads();

    // phase 2: h1 = fea @ w1g  (225x8 @ 8x64), swizzled store
    {
        const int o = tid & 63, mr = tid >> 6;
        const int g = o >> 2, e = o & 3;
        float wv[8];
#pragma unroll
        for (int k = 0; k < 8; ++k) wv[k] = w1g[k * 64 + o];
        for (int n = mr; n < 225; n += 4) {
            float acc = 0;
#pragma unroll
            for (int k = 0; k < 8; ++k) acc += att[n * 8 + k] * wv[k];
            h[hsw(n, g) + e] = acc;
        }
    }
    __syncthreads();

    // phase 2.5: asrc -> att[0..899]; adst -> registers (same task mapping as p3)
    float adnr[4];
#pragma unroll
    for (int r = 0; r < 4; ++r) {
        const int t = tid + 256 * r;
        if (t < 900) {
            const int n = t >> 2, hd = t & 3;
            float as = 0, ad = 0;
#pragma unroll
            for (int q = 0; q < 4; ++q) {
                const float4 hv = *reinterpret_cast<const float4*>(&h[hsw(n, hd * 4 + q)]);
                const float* s4 = &a1src[hd * 16 + q * 4];
                const float* d4 = &a1dst[hd * 16 + q * 4];
                as += hv.x * s4[0] + hv.y * s4[1] + hv.z * s4[2] + hv.w * s4[3];
                ad += hv.x * d4[0] + hv.y * d4[1] + hv.z * d4[2] + hv.w * d4[3];
            }
            att[t] = as;
            adnr[r] = ad;
        }
    }
    __syncthreads();

    // phase 3: GAT1 attention + relu + bias -> registers
    float o1[4][16];
#pragma unroll
    for (int r = 0; r < 4; ++r) {
        const int task = tid + 256 * r;
        if (task < 900) {
            const int n = task >> 2, hd = task & 3;
            const int i = n / 25, j = n % 25;
            const float adn = adnr[r];
            float e[9];
            int sid[9];
            float mx = -1e30f;
#pragma unroll
            for (int t9 = 0; t9 < 9; ++t9) {
                const int di = t9 / 3 - 1, dj = t9 % 3 - 1;
                const int ni = i + di, nj = j + dj;
                const bool valid = ((unsigned)ni < 9u) && ((unsigned)nj < 25u);
                const int s = valid ? ni * 25 + nj : n;
                sid[t9] = s;
                float ev = att[s * 4 + hd] + adn;
                ev = ev >= 0.f ? ev : 0.2f * ev;          // leaky_relu(0.2)
                e[t9] = valid ? ev : -1e30f;
                mx = fmaxf(mx, e[t9]);
            }
            float sum = 0;
#pragma unroll
            for (int t9 = 0; t9 < 9; ++t9) {
                float ex = __expf(e[t9] - mx);
                e[t9] = ex;
                sum += ex;
            }
            const float inv = 1.f / sum;
            float out[16] = {};
#pragma unroll
            for (int t9 = 0; t9 < 9; ++t9) {
                const float al = e[t9] * inv;
                const int s = sid[t9];
#pragma unroll
                for (int q = 0; q < 4; ++q) {
                    const float4 hv = *reinterpret_cast<const float4*>(&h[hsw(s, hd * 4 + q)]);
                    out[q * 4 + 0] += al * hv.x;
                    out[q * 4 + 1] += al * hv.y;
                    out[q * 4 + 2] += al * hv.z;
                    out[q * 4 + 3] += al * hv.w;
                }
            }
            const float* bp = b1g + hd * 16;
#pragma unroll
            for (int d = 0; d < 16; ++d) o1[r][d] = fmaxf(out[d] + bp[d], 0.f);
        }
    }
    __syncthreads();   // all reads of h1 complete

    // phase 4: x1 -> h region (swizzled float4 stores)
#pragma unroll
    for (int r = 0; r < 4; ++r) {
        const int task = tid + 256 * r;
        if (task < 900) {
            const int n = task >> 2, hd = task & 3;
#pragma unroll
            for (int q = 0; q < 4; ++q)
                *reinterpret_cast<float4*>(&h[hsw(n, hd * 4 + q)]) =
                    make_float4(o1[r][q * 4 + 0], o1[r][q * 4 + 1],
                                o1[r][q * 4 + 2], o1[r][q * 4 + 3]);
        }
    }
    __syncthreads();

    // phase 5: h2 = x1 @ w2g (225x64 @ 64x8) -> att as h2[8][225] (conflict-free)
    if (tid < 225) {
        const int n = tid;
        float acc8[8] = {};
#pragma unroll
        for (int g = 0; g < 16; ++g) {
            const float4 xv = *reinterpret_cast<const float4*>(&h[hsw(n, g)]);
            const int k = g * 4;
#pragma unroll
            for (int o = 0; o < 8; ++o) {
                acc8[o] += xv.x * w2g[k * 8 + o] + xv.y * w2g[(k + 1) * 8 + o]
                         + xv.z * w2g[(k + 2) * 8 + o] + xv.w * w2g[(k + 3) * 8 + o];
            }
        }
#pragma unroll
        for (int o = 0; o < 8; ++o) att[o * 225 + n] = acc8[o];
    }
    __syncthreads();

    // phase 6: GAT2 attention (1 head, d=8, mean==identity) -> flat (bf16)
    if (tid < 225) {
        const int n = tid, i = n / 25, j = n % 25;
        float av[8], dv[8];
#pragma unroll
        for (int d = 0; d < 8; ++d) { av[d] = a2src[d]; dv[d] = a2dst[d]; }
        float adn = 0;
#pragma unroll
        for (int d = 0; d < 8; ++d) adn += att[d * 225 + n] * dv[d];
        float e[9];
        int sid[9];
        float mx = -1e30f;
#pragma unroll
        for (int t9 = 0; t9 < 9; ++t9) {
            const int di = t9 / 3 - 1, dj = t9 % 3 - 1;
            const int ni = i + di, nj = j + dj;
            const bool valid = ((unsigned)ni < 9u) && ((unsigned)nj < 25u);
            const int s = valid ? ni * 25 + nj : n;
            sid[t9] = s;
            float as = 0;
#pragma unroll
            for (int d = 0; d < 8; ++d) as += att[d * 225 + s] * av[d];
            float ev = as + adn;
            ev = ev >= 0.f ? ev : 0.2f * ev;
            e[t9] = valid ? ev : -1e30f;
            mx = fmaxf(mx, e[t9]);
        }
        float sum = 0;
#pragma unroll
        for (int t9 = 0; t9 < 9; ++t9) {
            float ex = __expf(e[t9] - mx);
            e[t9] = ex;
            sum += ex;
        }
        const float inv = 1.f / sum;
        float out[8] = {};
#pragma unroll
        for (int t9 = 0; t9 < 9; ++t9) {
            const float al = e[t9] * inv;
            const int s = sid[t9];
#pragma unroll
            for (int d = 0; d < 8; ++d) out[d] += al * att[d * 225 + s];
        }
        short* dst = flat + (size_t)b * 1824 + n * 8;
#pragma unroll
        for (int d = 0; d < 8; ++d) dst[d] = f2bs(out[d] + b2g[d]);
    }
    // zero-pad K 1800 -> 1824 so fc1 has no boundary tile
    if (tid < 24) flat[(size_t)b * 1824 + 1800 + tid] = 0;
}

// ---------------------------------------------------------------------------
// Kernel 3/4: MFMA GEMM  C[128,N] = A_bf16[128,K] @ bf16(Wf[Kw,N]) (+bias, opt relu)
// BM=128, BK=32, 256 threads (4 waves), 16x16x32 bf16 MFMA.
// 3-stage pipeline: compute(cur) | STORE(cur^1)=tile kt+1 | LOAD(kt+2) | barrier.
// Load-to-consume distance = compute + barrier + compute (2x the old 2-stage),
// at identical register cost (STORE drains va/bv before LOAD refills them).
// LDS rows padded to 40 bf16 (80B, 16B-aligned, spread across all banks).
// ---------------------------------------------------------------------------
template <int BN, int MT, int NT, int NWN, bool RELU, bool OUT_BF16>
__global__ __launch_bounds__(256) void gemm_mfma(const short* __restrict__ A,
                                                 const float* __restrict__ Wf,
                                                 const float* __restrict__ bias,
                                                 void* __restrict__ outp,
                                                 int K, int Kw, int N) {
    constexpr int LDT = 40;
    __shared__ __align__(16) short sA[2][128 * LDT];
    __shared__ __align__(16) short sB[2][BN * LDT];   // transposed: [n][k]
    const int tid = threadIdx.x;
    const int lane = tid & 63;
    const int wave = tid >> 6;
    const int n0 = blockIdx.x * BN;
    const int wm0 = (wave / NWN) * (MT * 16);
    const int wn0 = (wave % NWN) * (NT * 16);
    const int lm = lane & 15;
    const int lkb = (lane >> 4) * 8;

    const int am = tid >> 1;          // A row 0..127
    const int akh = tid & 1;          // k half (16 elems)
    constexpr int EPT = (32 * BN) / 256;
    const int bn_ = tid % BN;
    const int bk0 = (tid / BN) * EPT;

    f32x4 acc[MT][NT] = {};
    const int nkt = K >> 5;           // K is a multiple of 32 by construction

    uint4 va0, va1;                   // staged A (32B/thread)
    float bv[EPT];                    // staged W (fp32, converted on ds_write)

    auto LOAD = [&](int kt) {
        const int k0 = kt << 5;
        const uint4* src = reinterpret_cast<const uint4*>(A + (size_t)am * K + k0 + akh * 16);
        va0 = src[0];
        va1 = src[1];
#pragma unroll
        for (int jj = 0; jj < EPT; ++jj) {
            int kk = k0 + bk0 + jj;
            if (kk >= Kw) kk = Kw - 1;              // A==0 there; avoid OOB/NaN
            bv[jj] = Wf[(size_t)kk * N + n0 + bn_];
        }
    };
    auto STORE = [&](int buf) {
        uint4* dstA = reinterpret_cast<uint4*>(&sA[buf][am * LDT + akh * 16]);
        dstA[0] = va0;
        dstA[1] = va1;
        unsigned uw[EPT / 2];
#pragma unroll
        for (int jj = 0; jj < EPT / 2; ++jj)
            uw[jj] = pack2(f2bs(bv[2 * jj]), f2bs(bv[2 * jj + 1]));
        if constexpr (EPT == 8) {
            uint4 u;
            u.x = uw[0]; u.y = uw[1]; u.z = uw[2]; u.w = uw[3];
            *reinterpret_cast<uint4*>(&sB[buf][bn_ * LDT + bk0]) = u;
        } else {
            *reinterpret_cast<unsigned*>(&sB[buf][bn_ * LDT + bk0]) = uw[0];
        }
    };

    LOAD(0);
    STORE(0);
    if (nkt > 1) LOAD(1);
    __syncthreads();

    int cur = 0;
    for (int kt = 0; kt < nkt; ++kt) {
        bh8_t bfr[NT];
#pragma unroll
        for (int nt = 0; nt < NT; ++nt)
            bfr[nt] = *reinterpret_cast<const bh8_t*>(&sB[cur][(wn0 + nt * 16 + lm) * LDT + lkb]);
#pragma unroll
        for (int mt = 0; mt < MT; ++mt) {
            bh8_t afr = *reinterpret_cast<const bh8_t*>(&sA[cur][(wm0 + mt * 16 + lm) * LDT + lkb]);
#pragma unroll
            for (int nt = 0; nt < NT; ++nt)
                acc[mt][nt] = __builtin_amdgcn_mfma_f32_16x16x32_bf16(afr, bfr[nt], acc[mt][nt], 0, 0, 0);
        }
        if (kt + 1 < nkt) STORE(cur ^ 1);       // tile kt+1 -> other buffer
        if (kt + 2 < nkt) LOAD(kt + 2);         // refill staging regs
        __syncthreads();                        // one barrier per k-tile
        cur ^= 1;
    }

    // epilogue: C/D layout col=lane&15, row=(lane>>4)*4+r  [m89 verified]
    const int rg = lane >> 4;
#pragma unroll
    for (int nt = 0; nt < NT; ++nt) {
        const int n = n0 + wn0 + nt * 16 + lm;
        const float bvv = bias[n];
#pragma unroll
        for (int mt = 0; mt < MT; ++mt) {
#pragma unroll
            for (int r = 0; r < 4; ++r) {
                const int m = wm0 + mt * 16 + rg * 4 + r;
                float v = acc[mt][nt][r] + bvv;
                if (RELU) v = fmaxf(v, 0.f);
                if (OUT_BF16)
                    reinterpret_cast<short*>(outp)[(size_t)m * N + n] = f2bs(v);
                else
                    reinterpret_cast<float*>(outp)[(size_t)m * N + n] = v;
            }
        }
    }
}

// ---------------------------------------------------------------------------
extern "C" void kernel_launch(void* const* d_in, const int* in_sizes, int n_in,
                              void* d_out, int out_size, void* d_ws, size_t ws_size,
                              hipStream_t stream) {
    const float* x4        = (const float*)d_in[0];
    const float* pool_w    = (const float*)d_in[1];
    const float* pool_b    = (const float*)d_in[2];
    const float* gat1_w    = (const float*)d_in[3];
    const float* gat1_asrc = (const float*)d_in[4];
    const float* gat1_adst = (const float*)d_in[5];
    const float* gat1_b    = (const float*)d_in[6];
    const float* gat2_w    = (const float*)d_in[7];
    const float* gat2_asrc = (const float*)d_in[8];
    const float* gat2_adst = (const float*)d_in[9];
    const float* gat2_b    = (const float*)d_in[10];
    const float* w1        = (const float*)d_in[11];
    const float* b1        = (const float*)d_in[12];
    const float* w2        = (const float*)d_in[13];
    const float* b2        = (const float*)d_in[14];
    // d_in[15] edge_index: fixed 9x25 grid, hardcoded in kernels.
    float* out = (float*)d_out;

    char* ws = (char*)d_ws;
    float* part = (float*)ws;                        // 128*8*1800*4 = 7,372,800 B
    short* flat = (short*)(ws + 7372800);            // 128*1824*2  =   466,944 B (K padded)
    short* hid  = (short*)(ws + 7372800 + 466944);   // 128*2048*2  =   524,288 B

    pool_kernel<<<1024, 256, 0, stream>>>(x4, pool_w, part);
    gat_kernel<<<128, 256, 0, stream>>>(part, pool_b, gat1_w, gat1_asrc, gat1_adst, gat1_b,
                                        gat2_w, gat2_asrc, gat2_adst, gat2_b, flat);
    // fc1: K=1824 (zero-padded, no boundary tile), Kw=1800, N=2048, relu, bf16 out
    gemm_mfma<16, 2, 1, 1, true, true><<<128, 256, 0, stream>>>(flat, w1, b1, (void*)hid, 1824, 1800, 2048);
    // fc2: K=2048, N=20800, fp32 out
    gemm_mfma<64, 4, 2, 2, false, false><<<325, 256, 0, stream>>>(hid, w2, b2, (void*)out, 2048, 2048, 20800);
}